// Round 2
// baseline (345.865 us; speedup 1.0000x reference)
//
#include <hip/hip_runtime.h>

#define BDIM 256
constexpr int Bn = 16, Cn = 4, Hn = 512, Wn = 512;
constexpr int SL   = Bn * Cn;          // 64 slices
constexpr int WPR  = Wn / 4;           // 128 int4/float4 words per row
constexpr int RPW  = 4;                // rows per wave
constexpr int RPB  = 16;               // rows per block (4 waves x 4 rows)
constexpr int CPB  = Hn / RPB;         // 32 chunks per slice
constexpr int NBLK = SL * CPB;         // 2048 blocks = 8 per CU -> 32 waves/CU
constexpr float NTOT = 16777216.0f;    // B*C*H*W
constexpr float SMOOTHF = 0.0001f;

__device__ __forceinline__ float wave_reduce(float v) {
#pragma unroll
    for (int off = 32; off > 0; off >>= 1) v += __shfl_down(v, off);
    return v;
}

__device__ __forceinline__ unsigned pack4(int4 c) {
    return (unsigned)c.x | ((unsigned)c.y << 8) |
           ((unsigned)c.z << 16) | ((unsigned)c.w << 24);
}

// ws layout (floats): [0..63] inter/slice, [64..127] i/slice, [128..191] j/slice,
// [192] ce, [193] ed, [194] (int) completion counter. Zeroed by memsetAsync.
//
// Streaming, single-kernel design. A wave's 64 lanes span one full 512-wide
// row (8 elems/lane): horizontal neighbors are 2 shfls (lane 0/63 edges are
// the zero pad), vertical neighbors roll through registers over 4 rows.
// Grid = 2048 blocks (8/CU); launch_bounds(256,8) caps VGPR at 64 so all
// 32 waves/CU are resident -> latency hiding by TLP, no LDS staging.
__global__ __launch_bounds__(BDIM, 8) void seg_main(const float4* __restrict__ cmap,
                                                    const int4* __restrict__ gt,
                                                    float* __restrict__ ws,
                                                    float* __restrict__ out) {
    __shared__ float sm[5][4];
    __shared__ int last_flag;

    const int tid   = threadIdx.x;
    const int lane  = tid & 63;
    const int wave  = tid >> 6;
    const int slice = blockIdx.x >> 5;        // / CPB
    const int chunk = blockIdx.x & (CPB - 1);
    const int R0    = chunk * RPB + wave * RPW;

    const float4* cm = cmap + slice * (Hn * WPR);
    const int4*   gs = gt   + slice * (Hn * WPR);
    const int wi = 2 * lane;                  // this lane: words wi, wi+1 (elems 8l..8l+7)

    // ---- prologue: rows R0-1 (up) and R0 (center), packed 1 byte/elem ----
    unsigned up0, up1, cu0, cu1;
    {
        const int rm = max(R0 - 1, 0);
        const int4 a = gs[rm * WPR + wi];
        const int4 b = gs[rm * WPR + wi + 1];
        up0 = pack4(a); up1 = pack4(b);
        if (R0 == 0) { up0 = 0u; up1 = 0u; }
        const int4 c = gs[R0 * WPR + wi];
        const int4 d = gs[R0 * WPR + wi + 1];
        cu0 = pack4(c); cu1 = pack4(d);
    }

    float cesum = 0.f, cxy = 0.f, ed = 0.f, inter = 0.f, jsum = 0.f;
    int icnt = 0;

#pragma unroll
    for (int r = R0; r < R0 + RPW; ++r) {
        // next-row gt (down neighbor / next center)
        unsigned dn0, dn1;
        {
            const int rn = min(r + 1, Hn - 1);
            const int4 a = gs[rn * WPR + wi];
            const int4 b = gs[rn * WPR + wi + 1];
            dn0 = pack4(a); dn1 = pack4(b);
            if (r + 1 >= Hn) { dn0 = 0u; dn1 = 0u; }
        }
        const float4 x0 = cm[r * WPR + wi];
        const float4 x1 = cm[r * WPR + wi + 1];

        // horizontal neighbors: intra-wave shfl; lane edges are the zero pad
        unsigned pw = __shfl_up(cu1, 1);   if (lane == 0)  pw = 0u;
        unsigned nw = __shfl_down(cu0, 1); if (lane == 63) nw = 0u;

        const unsigned lu0 = (cu0 << 8) | (pw >> 24);
        const unsigned ru0 = (cu0 >> 8) | ((cu1 & 0xffu) << 24);
        const unsigned lu1 = (cu1 << 8) | (cu0 >> 24);
        const unsigned ru1 = (cu1 >> 8) | (nw << 24);

        // byte-wise neighbor count, max 5 per byte -> no carry across bytes
        const unsigned s0 = cu0 + up0 + dn0 + lu0 + ru0;
        const unsigned s1 = cu1 + up1 + dn1 + lu1 + ru1;
        icnt += __popc(cu0) + __popc(cu1);   // bytes are 0/1

        const float xs[8] = {x0.x, x0.y, x0.z, x0.w, x1.x, x1.y, x1.z, x1.w};
#pragma unroll
        for (int e = 0; e < 8; ++e) {
            const unsigned cw = (e < 4) ? cu0 : cu1;
            const unsigned sw = (e < 4) ? s0 : s1;
            const int sh = 8 * (e & 3);
            const float xv = xs[e];
            const float t  = __expf(-fabsf(xv));            // exp(-|x|)
            const float u1 = 1.f + t;
            const float sp = fmaxf(xv, 0.f) + __logf(u1);   // softplus = logaddexp(0,x)
            const float r1 = __builtin_amdgcn_rcpf(u1);
            const float pred = (xv >= 0.f) ? r1 : t * r1;   // sigmoid(x)
            const float yf = (float)((cw >> sh) & 1u);

            cesum += sp;
            cxy   = fmaf(yf, xv, cxy);                      // ce = cesum - cxy
            inter = fmaf(yf, pred, inter);
            jsum += pred;
            const unsigned sb = (sw >> sh) & 0xffu;
            if (sb - 1u < 4u) ed += fminf(sp, 100.f);       // edge <=> 1<=s<=4
        }

        // roll vertical window
        up0 = cu0; up1 = cu1; cu0 = dn0; cu1 = dn1;
    }

    // ---- block reduction ----
    const float v0 = wave_reduce(cesum - cxy);
    const float v1 = wave_reduce(ed);
    const float v2 = wave_reduce(inter);
    const float v3 = wave_reduce((float)icnt);
    const float v4 = wave_reduce(jsum);
    if (lane == 0) {
        sm[0][wave] = v0; sm[1][wave] = v1; sm[2][wave] = v2;
        sm[3][wave] = v3; sm[4][wave] = v4;
    }
    __syncthreads();

    // ---- device-scope accumulation + last-block finish (no 2nd kernel) ----
    if (tid == 0) {
        const float bce = sm[0][0] + sm[0][1] + sm[0][2] + sm[0][3];
        const float bed = sm[1][0] + sm[1][1] + sm[1][2] + sm[1][3];
        const float bin = sm[2][0] + sm[2][1] + sm[2][2] + sm[2][3];
        const float bis = sm[3][0] + sm[3][1] + sm[3][2] + sm[3][3];
        const float bjs = sm[4][0] + sm[4][1] + sm[4][2] + sm[4][3];
        atomicAdd(&ws[slice],       bin);
        atomicAdd(&ws[64 + slice],  bis);
        atomicAdd(&ws[128 + slice], bjs);
        atomicAdd(&ws[192], bce);
        atomicAdd(&ws[193], bed);
        __threadfence();                      // publish before counter bump
        const int old = __hip_atomic_fetch_add((int*)(ws + 194), 1,
                                               __ATOMIC_ACQ_REL,
                                               __HIP_MEMORY_SCOPE_AGENT);
        last_flag = (old == NBLK - 1);
    }
    __syncthreads();

    if (last_flag && wave == 0) {             // one wave finishes the loss
        const float in_s = __hip_atomic_load(&ws[lane],       __ATOMIC_RELAXED, __HIP_MEMORY_SCOPE_AGENT);
        const float i_s  = __hip_atomic_load(&ws[64 + lane],  __ATOMIC_RELAXED, __HIP_MEMORY_SCOPE_AGENT);
        const float j_s  = __hip_atomic_load(&ws[128 + lane], __ATOMIC_RELAXED, __HIP_MEMORY_SCOPE_AGENT);
        const float score = (2.f * in_s + SMOOTHF) / (i_s + j_s + SMOOTHF);
        float dice = (1.f - score) * (1.f / (float)Bn);   // mean over batch
        dice = wave_reduce(dice);                         // sum over 64 slices
        if (lane == 0) {
            const float ce = __hip_atomic_load(&ws[192], __ATOMIC_RELAXED, __HIP_MEMORY_SCOPE_AGENT);
            const float edl = __hip_atomic_load(&ws[193], __ATOMIC_RELAXED, __HIP_MEMORY_SCOPE_AGENT);
            out[0] = (ce + edl) * (1.f / NTOT) + dice;
        }
    }
}

extern "C" void kernel_launch(void* const* d_in, const int* in_sizes, int n_in,
                              void* d_out, int out_size, void* d_ws, size_t ws_size,
                              hipStream_t stream) {
    const float4* cmap = (const float4*)d_in[0];
    const int4*   gt   = (const int4*)d_in[1];
    float* ws = (float*)d_ws;
    hipMemsetAsync(ws, 0, 195 * sizeof(float) + sizeof(int), stream);
    seg_main<<<NBLK, BDIM, 0, stream>>>(cmap, gt, ws, (float*)d_out);
}

// Round 3
// 147.501 us; speedup vs baseline: 2.3448x; 2.3448x over previous
//
#include <hip/hip_runtime.h>

#define BDIM 256
constexpr int Bn = 16, Cn = 4, Hn = 512, Wn = 512;
constexpr int SL   = Bn * Cn;          // 64 slices
constexpr int WPR  = Wn / 4;           // 128 int4/float4 words per row
constexpr int RPW  = 4;                // rows per wave
constexpr int RPB  = 16;               // rows per block (4 waves x 4 rows)
constexpr int CPB  = Hn / RPB;         // 32 chunks per slice
constexpr int NBLK = SL * CPB;         // 2048 blocks = 8 per CU -> 32 waves/CU
constexpr float NTOT = 16777216.0f;    // B*C*H*W
constexpr float SMOOTHF = 0.0001f;

__device__ __forceinline__ float wave_reduce(float v) {
#pragma unroll
    for (int off = 32; off > 0; off >>= 1) v += __shfl_down(v, off);
    return v;
}

__device__ __forceinline__ unsigned pack4(int4 c) {
    return (unsigned)c.x | ((unsigned)c.y << 8) |
           ((unsigned)c.z << 16) | ((unsigned)c.w << 24);
}

// Streaming, fence-free design. A wave's 64 lanes span one full 512-wide row
// (8 elems/lane): horizontal neighbors are 2 shfls (lane 0/63 edges are the
// zero pad), vertical neighbors roll through registers over 4 rows.
// 2048 blocks (8/CU) + launch_bounds(256,8) -> up to 32 waves/CU resident.
// Explicit prefetch pipeline: next row's cmap+gt loads issue BEFORE current
// row's compute, so each wave keeps ~4 16B loads in flight (round-1 compiler
// schedule collapsed MLP to ~1-2; that was the latency bottleneck).
// NO device-scope atomics/fences: round 2 showed per-block agent-scope
// fences flush L2 (WRITE_SIZE 214 MB, FETCH +117 MB) -> 5x regression.
__global__ __launch_bounds__(BDIM, 8) void seg_main(const float4* __restrict__ cmap,
                                                    const int4* __restrict__ gt,
                                                    float* __restrict__ ws) {
    __shared__ float sm[5][4];

    const int tid   = threadIdx.x;
    const int lane  = tid & 63;
    const int wave  = tid >> 6;
    const int slice = blockIdx.x >> 5;        // / CPB
    const int chunk = blockIdx.x & (CPB - 1);
    const int R0    = chunk * RPB + wave * RPW;

    const float4* cm = cmap + slice * (Hn * WPR);
    const int4*   gs = gt   + slice * (Hn * WPR);
    const int wi = 2 * lane;                  // this lane: words wi, wi+1 (elems 8l..8l+7)

    // ---- prologue: 8 independent loads issued back-to-back ----
    unsigned up0, up1, cu0, cu1, dn0, dn1;
    float4 x0, x1;
    {
        const int rm  = max(R0 - 1, 0);
        const int4 a = gs[rm * WPR + wi];
        const int4 b = gs[rm * WPR + wi + 1];
        const int4 c = gs[R0 * WPR + wi];
        const int4 d = gs[R0 * WPR + wi + 1];
        const int4 e = gs[(R0 + 1) * WPR + wi];      // R0+1 <= 509 < Hn always
        const int4 f = gs[(R0 + 1) * WPR + wi + 1];
        x0 = cm[R0 * WPR + wi];
        x1 = cm[R0 * WPR + wi + 1];
        up0 = pack4(a); up1 = pack4(b);
        if (R0 == 0) { up0 = 0u; up1 = 0u; }
        cu0 = pack4(c); cu1 = pack4(d);
        dn0 = pack4(e); dn1 = pack4(f);
    }

    float cesum = 0.f, cxy = 0.f, ed = 0.f, inter = 0.f, jsum = 0.f;
    int icnt = 0;

#pragma unroll
    for (int i = 0; i < RPW; ++i) {
        const int r = R0 + i;

        // ---- prefetch for iteration i+1 (issued before current compute) ----
        int4 pa, pb; float4 nx0, nx1;
        if (i < RPW - 1) {                    // compile-time after unroll
            const int rn = min(r + 2, Hn - 1);
            pa  = gs[rn * WPR + wi];
            pb  = gs[rn * WPR + wi + 1];
            nx0 = cm[(r + 1) * WPR + wi];
            nx1 = cm[(r + 1) * WPR + wi + 1];
        }

        // ---- compute row r ----
        // horizontal neighbors: intra-wave shfl; lane edges are the zero pad
        unsigned pw = __shfl_up(cu1, 1);   if (lane == 0)  pw = 0u;
        unsigned nw = __shfl_down(cu0, 1); if (lane == 63) nw = 0u;

        const unsigned lu0 = (cu0 << 8) | (pw >> 24);
        const unsigned ru0 = (cu0 >> 8) | ((cu1 & 0xffu) << 24);
        const unsigned lu1 = (cu1 << 8) | (cu0 >> 24);
        const unsigned ru1 = (cu1 >> 8) | (nw << 24);

        // byte-wise neighbor count, max 5 per byte -> no carry across bytes
        const unsigned s0 = cu0 + up0 + dn0 + lu0 + ru0;
        const unsigned s1 = cu1 + up1 + dn1 + lu1 + ru1;
        icnt += __popc(cu0) + __popc(cu1);   // bytes are 0/1

        const float xs[8] = {x0.x, x0.y, x0.z, x0.w, x1.x, x1.y, x1.z, x1.w};
#pragma unroll
        for (int e = 0; e < 8; ++e) {
            const unsigned cw = (e < 4) ? cu0 : cu1;
            const unsigned sw = (e < 4) ? s0 : s1;
            const int sh = 8 * (e & 3);
            const float xv = xs[e];
            const float t  = __expf(-fabsf(xv));            // exp(-|x|)
            const float u1 = 1.f + t;
            const float sp = fmaxf(xv, 0.f) + __logf(u1);   // softplus = logaddexp(0,x)
            const float r1 = __builtin_amdgcn_rcpf(u1);
            const float pred = (xv >= 0.f) ? r1 : t * r1;   // sigmoid(x)
            const float yf = (float)((cw >> sh) & 1u);

            cesum += sp;
            cxy   = fmaf(yf, xv, cxy);                      // ce = cesum - cxy
            inter = fmaf(yf, pred, inter);
            jsum += pred;
            const unsigned sb = (sw >> sh) & 0xffu;
            if (sb - 1u < 4u) ed += fminf(sp, 100.f);       // edge <=> 1<=s<=4
        }

        // ---- roll vertical window with prefetched data ----
        if (i < RPW - 1) {
            up0 = cu0; up1 = cu1; cu0 = dn0; cu1 = dn1;
            unsigned t0 = pack4(pa), t1 = pack4(pb);
            if (r + 2 >= Hn) { t0 = 0u; t1 = 0u; }
            dn0 = t0; dn1 = t1;
            x0 = nx0; x1 = nx1;
        }
    }

    // ---- block reduction, one write per partial, no atomics ----
    const float v0 = wave_reduce(cesum - cxy);
    const float v1 = wave_reduce(ed);
    const float v2 = wave_reduce(inter);
    const float v3 = wave_reduce((float)icnt);
    const float v4 = wave_reduce(jsum);
    if (lane == 0) {
        sm[0][wave] = v0; sm[1][wave] = v1; sm[2][wave] = v2;
        sm[3][wave] = v3; sm[4][wave] = v4;
    }
    __syncthreads();
    if (tid < 5)
        ws[tid * NBLK + blockIdx.x] = sm[tid][0] + sm[tid][1] + sm[tid][2] + sm[tid][3];
}

__global__ void seg_finish(const float* __restrict__ ws, float* __restrict__ out) {
    const int t = threadIdx.x;                // 64 threads, one per (b,c) slice
    float ce = 0.f, ed = 0.f, inter = 0.f, is = 0.f, js = 0.f;
#pragma unroll 8
    for (int i = 0; i < CPB; ++i) {
        const int b = t * CPB + i;
        ce    += ws[0 * NBLK + b];
        ed    += ws[1 * NBLK + b];
        inter += ws[2 * NBLK + b];
        is    += ws[3 * NBLK + b];
        js    += ws[4 * NBLK + b];
    }
    const float score = (2.f * inter + SMOOTHF) / (is + js + SMOOTHF);
    float dice = (1.f - score) * (1.f / (float)Bn);   // mean over batch
    dice = wave_reduce(dice);                         // sum over classes (64 slices)
    ce = wave_reduce(ce);
    ed = wave_reduce(ed);
    if (t == 0)
        out[0] = ce * (1.f / NTOT) + ed * (1.f / NTOT) + dice;
}

extern "C" void kernel_launch(void* const* d_in, const int* in_sizes, int n_in,
                              void* d_out, int out_size, void* d_ws, size_t ws_size,
                              hipStream_t stream) {
    const float4* cmap = (const float4*)d_in[0];
    const int4*   gt   = (const int4*)d_in[1];
    float* ws = (float*)d_ws;                 // 5 * 2048 floats, fully rewritten
    seg_main<<<NBLK, BDIM, 0, stream>>>(cmap, gt, ws);
    seg_finish<<<1, 64, 0, stream>>>(ws, (float*)d_out);
}